// Round 12
// baseline (1035.536 us; speedup 1.0000x reference)
//
#include <hip/hip_runtime.h>

// ============================================================================
// CategoryHead r12: r8 chain verbatim (bit-exact, absmax 0.00390625) with
// BS halved 32 -> 16 samples (32 token rows, 4096 blocks).
//  Rationale: r11 proved 3 waves/SIMD is reachable but its intra-block split
//  added LDS traffic and the forced VGPR cap spilled (53MB scratch). Halving
//  the block halves per-thread accumulator liveness NATURALLY (QKV acc 96->48
//  f32) with zero added instructions -> 3-4 blocks/CU co-resident, barriers
//  overlap across blocks. No launch-bounds cap -> no spills.
//  All per-element arithmetic chains identical to r8.
// ============================================================================

#define DEV static __device__ __forceinline__

typedef __attribute__((ext_vector_type(8))) short short8;
typedef __attribute__((ext_vector_type(4))) float f32x4;

#define BS    16
#define MROWS 32
#define PITCH 136
#define XP    272
#define LEPS  1e-5f

#define OFF_TPW  0
#define OFF_QKVW 65536
#define OFF_OUTW 262144
#define OFF_FF1W 327680
#define OFF_FF2W 589824
#define WS_ELEMS 851968

DEV unsigned short f2b(float f) {            // f32 -> bf16 (RNE)  [r1 verbatim]
  unsigned u = __float_as_uint(f);
  return (unsigned short)((u + 0x7fffu + ((u >> 16) & 1u)) >> 16);
}
DEV float b2f(unsigned short s) { return __uint_as_float((unsigned)s << 16); }

DEV f32x4 MFMA(short8 a, short8 b, f32x4 c) {
  return __builtin_amdgcn_mfma_f32_16x16x32_bf16(a, b, c, 0, 0, 0);
}

DEV float gelu_f(float x) {                  // [r1 verbatim]
  float u = 0.7978845608028654f * (x + 0.044715f * x * x * x);
  float e = __expf(2.0f * u);
  float t = 1.0f - 2.0f / (e + 1.0f);
  return 0.5f * x * (1.0f + t);
}

DEV short8 ldfrag(const unsigned short* tile, int rowBase, int kk, int lane) {
  return *(const short8*)(tile + (rowBase + (lane & 15)) * PITCH + kk * 32 + (lane >> 4) * 8);
}
DEV short8 ldfragX(const unsigned short* tile, int rowBase, int koff, int lane) {
  return *(const short8*)(tile + (rowBase + (lane & 15)) * XP + koff + (lane >> 4) * 8);
}
DEV short8 ldBg(const unsigned short* __restrict__ base, int pitch, int colBase,
                int koff, int kk, int lane) {
  return *(const short8*)(base + (size_t)(colBase + (lane & 15)) * pitch +
                          koff + kk * 32 + (lane >> 4) * 8);
}

// [r8 verbatim, rows halved] residual-added val[2][2] -> LN -> bf16 into sTok
DEV void ln_residual_write(f32x4 (&val)[2][2], const float* __restrict__ w,
                           const float* __restrict__ b, unsigned short* sTok,
                           float* sRedP, float* sRedF, int tid) {
  const int wave = tid >> 6, lane = tid & 63, g = lane >> 4, j = lane & 15;
  float ps[2][4], pq[2][4];
#pragma unroll
  for (int rt = 0; rt < 2; ++rt)
#pragma unroll
    for (int r = 0; r < 4; ++r) {
      float v0 = val[0][rt][r], v1 = val[1][rt][r];
      float s = v0 + v1, q = v0 * v0 + v1 * v1;
#pragma unroll
      for (int m = 1; m < 16; m <<= 1) {
        s += __shfl_xor(s, m, 16);
        q += __shfl_xor(q, m, 16);
      }
      ps[rt][r] = s; pq[rt][r] = q;
    }
  if (j == 0) {
#pragma unroll
    for (int rt = 0; rt < 2; ++rt)
#pragma unroll
      for (int r = 0; r < 4; ++r) {
        int row = rt * 16 + g * 4 + r;
        sRedP[row * 8 + wave * 2]     = ps[rt][r];
        sRedP[row * 8 + wave * 2 + 1] = pq[rt][r];
      }
  }
  __syncthreads();
  if (tid < MROWS) {
    float s = 0.f, q = 0.f;
#pragma unroll
    for (int wv = 0; wv < 4; ++wv) {
      s += sRedP[tid * 8 + wv * 2];
      q += sRedP[tid * 8 + wv * 2 + 1];
    }
    float mean = s * (1.f / 128.f);
    sRedF[tid * 2]     = mean;
    sRedF[tid * 2 + 1] = rsqrtf(q * (1.f / 128.f) - mean * mean + LEPS);
  }
  __syncthreads();
#pragma unroll
  for (int h = 0; h < 2; ++h) {
    int n = (h * 4 + wave) * 16 + j;
    float wn = w[n], bn = b[n];
#pragma unroll
    for (int rt = 0; rt < 2; ++rt)
#pragma unroll
      for (int r = 0; r < 4; ++r) {
        int row = rt * 16 + g * 4 + r;
        float mean = sRedF[row * 2], rstd = sRedF[row * 2 + 1];
        sTok[row * PITCH + n] = f2b((val[h][rt][r] - mean) * rstd * wn + bn);
      }
  }
  __syncthreads();
}

__global__ __launch_bounds__(256)
void prep_w(const float* __restrict__ tpw, const float* __restrict__ qkvw,
            const float* __restrict__ outw, const float* __restrict__ ff1w,
            const float* __restrict__ ff2w, unsigned short* __restrict__ wsb) {
  int i = blockIdx.x * 256 + threadIdx.x;
  if (i >= WS_ELEMS) return;
  float v;
  if (i < OFF_QKVW)      v = tpw[i - OFF_TPW];
  else if (i < OFF_OUTW) v = qkvw[i - OFF_QKVW];
  else if (i < OFF_FF1W) v = outw[i - OFF_OUTW];
  else if (i < OFF_FF2W) v = ff1w[i - OFF_FF1W];
  else                   v = ff2w[i - OFF_FF2W];
  wsb[i] = f2b(v);
}

__global__ __launch_bounds__(256)
void tx_fused(const float* __restrict__ x, const unsigned short* __restrict__ wsb,
              const float* __restrict__ tpb, const float* __restrict__ pos,
              const float* __restrict__ qkvb, const float* __restrict__ outb,
              const float* __restrict__ ln1w, const float* __restrict__ ln1b,
              const float* __restrict__ ff1b, const float* __restrict__ ff2b,
              const float* __restrict__ ln2w, const float* __restrict__ ln2b,
              const float* __restrict__ lnfw, const float* __restrict__ lnfb,
              const float* __restrict__ clnw, const float* __restrict__ clnb,
              const float* __restrict__ cw, const float* __restrict__ cb,
              float* __restrict__ out) {
  __shared__ __align__(16) unsigned short sTok[MROWS * PITCH];
  __shared__ __align__(16) unsigned short sStage[MROWS * PITCH]; // x[16][272] / o / h
  __shared__ float sRedP[MROWS * 8];
  __shared__ float sRedF[MROWS * 2];

  const int tid  = threadIdx.x;
  const int wave = tid >> 6;
  const int lane = tid & 63;
  const int g = lane >> 4, j = lane & 15;
  const size_t s0 = (size_t)blockIdx.x * BS;

  const unsigned short* tpwB  = wsb + OFF_TPW;
  const unsigned short* qkvwB = wsb + OFF_QKVW;
  const unsigned short* outwB = wsb + OFF_OUTW;
  const unsigned short* ff1wB = wsb + OFF_FF1W;
  const unsigned short* ff2wB = wsb + OFF_FF2W;

  const f32x4 zero4 = {0.f, 0.f, 0.f, 0.f};

  // ---- stage x (16 rows x 256, f2b RNE) [r8 verbatim values] ---------------
  {
    int idx = tid;                           // 16 rows x 16 segs
    int r = idx >> 4, s = idx & 15;
    const float4* p = (const float4*)(x + (s0 + r) * 256 + s * 16);
    float4 f0 = p[0], f1 = p[1], f2 = p[2], f3 = p[3];
    short8 lo, hi;
    lo[0] = (short)f2b(f0.x); lo[1] = (short)f2b(f0.y);
    lo[2] = (short)f2b(f0.z); lo[3] = (short)f2b(f0.w);
    lo[4] = (short)f2b(f1.x); lo[5] = (short)f2b(f1.y);
    lo[6] = (short)f2b(f1.z); lo[7] = (short)f2b(f1.w);
    hi[0] = (short)f2b(f2.x); hi[1] = (short)f2b(f2.y);
    hi[2] = (short)f2b(f2.z); hi[3] = (short)f2b(f2.w);
    hi[4] = (short)f2b(f3.x); hi[5] = (short)f2b(f3.y);
    hi[6] = (short)f2b(f3.z); hi[7] = (short)f2b(f3.w);
    *(short8*)(sStage + r * XP + s * 16)     = lo;
    *(short8*)(sStage + r * XP + s * 16 + 8) = hi;
  }
  __syncthreads();

  // ---- token projection: [16][256] @ tpw^T [r8 verbatim order] -------------
  f32x4 accTP[2][2];
#pragma unroll
  for (int nc = 0; nc < 2; ++nc)
#pragma unroll
    for (int h = 0; h < 2; ++h) accTP[nc][h] = zero4;

#pragma unroll
  for (int kc = 0; kc < 2; ++kc)
#pragma unroll
    for (int nc = 0; nc < 2; ++nc)
#pragma unroll
      for (int h = 0; h < 2; ++h) {
        int cb = nc * 128 + (h * 4 + wave) * 16;
        short8 bf[4];
#pragma unroll
        for (int kk = 0; kk < 4; ++kk)
          bf[kk] = ldBg(tpwB, 256, cb, kc * 128, kk, lane);
#pragma unroll
        for (int kk = 0; kk < 4; ++kk)
          accTP[nc][h] = MFMA(ldfragX(sStage, 0, kc * 128 + kk * 32, lane),
                              bf[kk], accTP[nc][h]);
      }
  __syncthreads();
  // tp epilogue [r8 verbatim]
#pragma unroll
  for (int nc = 0; nc < 2; ++nc)
#pragma unroll
    for (int h = 0; h < 2; ++h) {
      int d = (h * 4 + wave) * 16 + j;
      float bias = tpb[nc * 128 + d] + pos[nc * 128 + d];
#pragma unroll
      for (int r = 0; r < 4; ++r) {
        int sm = g * 4 + r;
        sTok[(2 * sm + nc) * PITCH + d] = f2b(accTP[nc][h][r] + bias);
      }
    }
  __syncthreads();

  // ============================== layers ===================================
  for (int li = 0; li < 4; ++li) {
    const unsigned short* qkvL = qkvwB + (size_t)li * 49152;
    const unsigned short* outL = outwB + (size_t)li * 16384;
    const unsigned short* ff1L = ff1wB + (size_t)li * 65536;
    const unsigned short* ff2L = ff2wB + (size_t)li * 65536;

    // ---- QKV [r8 verbatim, rows halved] ----
    short8 aT[2][4];
#pragma unroll
    for (int rt = 0; rt < 2; ++rt)
#pragma unroll
      for (int kk = 0; kk < 4; ++kk) aT[rt][kk] = ldfrag(sTok, rt * 16, kk, lane);

    f32x4 acc[6][2];
#pragma unroll
    for (int a = 0; a < 6; ++a)
#pragma unroll
      for (int rt = 0; rt < 2; ++rt) acc[a][rt] = zero4;

#pragma unroll
    for (int nc = 0; nc < 3; ++nc)
#pragma unroll
      for (int h = 0; h < 2; ++h) {
        int cb = nc * 128 + (h * 4 + wave) * 16;
        short8 bf[4];
#pragma unroll
        for (int kk = 0; kk < 4; ++kk) bf[kk] = ldBg(qkvL, 128, cb, 0, kk, lane);
        int a = nc * 2 + h;
#pragma unroll
        for (int rt = 0; rt < 2; ++rt)
#pragma unroll
          for (int kk = 0; kk < 4; ++kk)
            acc[a][rt] = MFMA(aT[rt][kk], bf[kk], acc[a][rt]);
      }
#pragma unroll
    for (int a = 0; a < 6; ++a) {
      int nc = a >> 1, h = a & 1;
      float bv = qkvb[li * 384 + nc * 128 + (h * 4 + wave) * 16 + j];
#pragma unroll
      for (int rt = 0; rt < 2; ++rt) acc[a][rt] += bv;
    }

    // ---- attention [r8 verbatim, rows halved] ----
#pragma unroll
    for (int hh = 0; hh < 2; ++hh) {
      int head = hh * 4 + wave;
#pragma unroll
      for (int rt = 0; rt < 2; ++rt)
#pragma unroll
        for (int sp = 0; sp < 2; ++sp) {
          int r0 = sp * 2, r1 = r0 + 1;
          float q0 = acc[hh][rt][r0],     q1 = acc[hh][rt][r1];
          float k0 = acc[2 + hh][rt][r0], k1 = acc[2 + hh][rt][r1];
          float s00 = q0 * k0, s01 = q0 * k1, s10 = q1 * k0, s11 = q1 * k1;
#pragma unroll
          for (int m = 1; m < 16; m <<= 1) {
            s00 += __shfl_xor(s00, m, 16);
            s01 += __shfl_xor(s01, m, 16);
            s10 += __shfl_xor(s10, m, 16);
            s11 += __shfl_xor(s11, m, 16);
          }
          s00 *= 0.25f; s01 *= 0.25f; s10 *= 0.25f; s11 *= 0.25f;
          float m0 = fmaxf(s00, s01), m1 = fmaxf(s10, s11);
          float e00 = __expf(s00 - m0), e01 = __expf(s01 - m0);
          float e10 = __expf(s10 - m1), e11 = __expf(s11 - m1);
          float i0 = 1.f / (e00 + e01), i1 = 1.f / (e10 + e11);
          float v0 = acc[4 + hh][rt][r0], v1 = acc[4 + hh][rt][r1];
          float o0 = (e00 * v0 + e01 * v1) * i0;
          float o1 = (e10 * v0 + e11 * v1) * i1;
          int rowb = rt * 16 + g * 4 + r0;
          int col  = head * 16 + j;
          sStage[rowb * PITCH + col]       = f2b(o0);
          sStage[(rowb + 1) * PITCH + col] = f2b(o1);
        }
    }
    __syncthreads();

    // ---- out-proj [r8 verbatim, rows halved] ----
    short8 aO[2][4];
#pragma unroll
    for (int rt = 0; rt < 2; ++rt)
#pragma unroll
      for (int kk = 0; kk < 4; ++kk) aO[rt][kk] = ldfrag(sStage, rt * 16, kk, lane);

    f32x4 accO[2][2];
#pragma unroll
    for (int h = 0; h < 2; ++h)
#pragma unroll
      for (int rt = 0; rt < 2; ++rt) accO[h][rt] = zero4;
#pragma unroll
    for (int h = 0; h < 2; ++h) {
      int cb = (h * 4 + wave) * 16;
      short8 bf[4];
#pragma unroll
      for (int kk = 0; kk < 4; ++kk) bf[kk] = ldBg(outL, 128, cb, 0, kk, lane);
#pragma unroll
      for (int rt = 0; rt < 2; ++rt)
#pragma unroll
        for (int kk = 0; kk < 4; ++kk)
          accO[h][rt] = MFMA(aO[rt][kk], bf[kk], accO[h][rt]);
    }
#pragma unroll
    for (int h = 0; h < 2; ++h) {
      int n = (h * 4 + wave) * 16 + j;
      float ob = outb[li * 128 + n];
#pragma unroll
      for (int rt = 0; rt < 2; ++rt)
#pragma unroll
        for (int r = 0; r < 4; ++r) {
          int row = rt * 16 + g * 4 + r;
          accO[h][rt][r] += ob + b2f(sTok[row * PITCH + n]);
        }
    }
    ln_residual_write(accO, ln1w + li * 128, ln1b + li * 128, sTok, sRedP, sRedF, tid);

    // ---- FFN [r8 verbatim, rows halved] ----
    short8 aF[2][4];
#pragma unroll
    for (int rt = 0; rt < 2; ++rt)
#pragma unroll
      for (int kk = 0; kk < 4; ++kk) aF[rt][kk] = ldfrag(sTok, rt * 16, kk, lane);

    f32x4 accF[2][2];
#pragma unroll
    for (int h = 0; h < 2; ++h)
#pragma unroll
      for (int rt = 0; rt < 2; ++rt) accF[h][rt] = zero4;

    for (int fc = 0; fc < 4; ++fc) {
      f32x4 hacc[2][2];
#pragma unroll
      for (int h = 0; h < 2; ++h)
#pragma unroll
        for (int rt = 0; rt < 2; ++rt) hacc[h][rt] = zero4;
#pragma unroll
      for (int h = 0; h < 2; ++h) {
        int cb = fc * 128 + (h * 4 + wave) * 16;
        short8 bf[4];
#pragma unroll
        for (int kk = 0; kk < 4; ++kk) bf[kk] = ldBg(ff1L, 128, cb, 0, kk, lane);
#pragma unroll
        for (int rt = 0; rt < 2; ++rt)
#pragma unroll
          for (int kk = 0; kk < 4; ++kk)
            hacc[h][rt] = MFMA(aF[rt][kk], bf[kk], hacc[h][rt]);
      }
      __syncthreads();   // prev chunk's aH reads complete before overwrite
#pragma unroll
      for (int h = 0; h < 2; ++h) {
        int nl = (h * 4 + wave) * 16 + j;
        float bb = ff1b[li * 512 + fc * 128 + nl];
#pragma unroll
        for (int rt = 0; rt < 2; ++rt)
#pragma unroll
          for (int r = 0; r < 4; ++r) {
            float hv = gelu_f(hacc[h][rt][r] + bb);
            sStage[(rt * 16 + g * 4 + r) * PITCH + nl] = f2b(hv);
          }
      }
      __syncthreads();   // h chunk visible
      short8 aH[2][4];
#pragma unroll
      for (int rt = 0; rt < 2; ++rt)
#pragma unroll
        for (int kk = 0; kk < 4; ++kk) aH[rt][kk] = ldfrag(sStage, rt * 16, kk, lane);
#pragma unroll
      for (int h = 0; h < 2; ++h) {
        int cb = (h * 4 + wave) * 16;
        short8 bf[4];
#pragma unroll
        for (int kk = 0; kk < 4; ++kk)
          bf[kk] = ldBg(ff2L, 512, cb, fc * 128, kk, lane);
#pragma unroll
        for (int rt = 0; rt < 2; ++rt)
#pragma unroll
          for (int kk = 0; kk < 4; ++kk)
            accF[h][rt] = MFMA(aH[rt][kk], bf[kk], accF[h][rt]);
      }
    }
#pragma unroll
    for (int h = 0; h < 2; ++h) {
      int n = (h * 4 + wave) * 16 + j;
      float fb = ff2b[li * 128 + n];
#pragma unroll
      for (int rt = 0; rt < 2; ++rt)
#pragma unroll
        for (int r = 0; r < 4; ++r) {
          int row = rt * 16 + g * 4 + r;
          accF[h][rt][r] += fb + b2f(sTok[row * PITCH + n]);
        }
    }
    ln_residual_write(accF, ln2w + li * 128, ln2b + li * 128, sTok, sRedP, sRedF, tid);
  }

  // ======= final LN -> pool -> cls head [r8 verbatim, 128 active threads] ===
  if (tid < 128) {
    int row = tid >> 2, q4 = tid & 3;
    const unsigned short* rp = sTok + row * PITCH + q4 * 32;
    float vb[32];
    float s = 0.f, sq = 0.f;
#pragma unroll
    for (int t8 = 0; t8 < 4; ++t8) {
      short8 v = *(const short8*)(rp + t8 * 8);
#pragma unroll
      for (int e = 0; e < 8; ++e) {
        float f = b2f((unsigned short)v[e]);
        vb[t8 * 8 + e] = f; s += f; sq += f * f;
      }
    }
    s  += __shfl_xor(s, 1, 4);  s  += __shfl_xor(s, 2, 4);
    sq += __shfl_xor(sq, 1, 4); sq += __shfl_xor(sq, 2, 4);
    float mean = s * (1.f / 128.f);
    float rstd = rsqrtf(sq * (1.f / 128.f) - mean * mean + LEPS);
    unsigned short* wp = sTok + row * PITCH + q4 * 32;
#pragma unroll
    for (int c = 0; c < 32; ++c) {
      int col = q4 * 32 + c;
      wp[c] = f2b((vb[c] - mean) * rstd * lnfw[col] + lnfb[col]);
    }
  }
  __syncthreads();
  if (tid < 128) {
    int sIdx = tid >> 3, oct = tid & 7;
    float pv[16];
    float s = 0.f, sq = 0.f;
#pragma unroll
    for (int t8 = 0; t8 < 2; ++t8) {
      short8 va  = *(const short8*)(sTok + (2 * sIdx) * PITCH + oct * 16 + t8 * 8);
      short8 vb2 = *(const short8*)(sTok + (2 * sIdx + 1) * PITCH + oct * 16 + t8 * 8);
#pragma unroll
      for (int e = 0; e < 8; ++e) {
        float f = 0.5f * (b2f((unsigned short)va[e]) + b2f((unsigned short)vb2[e]));
        pv[t8 * 8 + e] = f; s += f; sq += f * f;
      }
    }
    s  += __shfl_xor(s, 1, 8);  s  += __shfl_xor(s, 2, 8);  s  += __shfl_xor(s, 4, 8);
    sq += __shfl_xor(sq, 1, 8); sq += __shfl_xor(sq, 2, 8); sq += __shfl_xor(sq, 4, 8);
    float mean = s * (1.f / 128.f);
    float rstd = rsqrtf(sq * (1.f / 128.f) - mean * mean + LEPS);
    float gv[16];
#pragma unroll
    for (int c = 0; c < 16; ++c) {
      int col = oct * 16 + c;
      gv[c] = gelu_f((pv[c] - mean) * rstd * clnw[col] + clnb[col]);
    }
#pragma unroll
    for (int cc = 0; cc < 7; ++cc) {
      float p = 0.f;
#pragma unroll
      for (int c = 0; c < 16; ++c) p += gv[c] * cw[cc * 128 + oct * 16 + c];
      p += __shfl_xor(p, 1, 8); p += __shfl_xor(p, 2, 8); p += __shfl_xor(p, 4, 8);
      if (oct == 0) out[(s0 + sIdx) * 7 + cc] = p + cb[cc];
    }
  }
}

extern "C" void kernel_launch(void* const* d_in, const int* in_sizes, int n_in,
                              void* d_out, int out_size, void* d_ws, size_t ws_size,
                              hipStream_t stream) {
  (void)n_in; (void)out_size; (void)ws_size;
  const float* x    = (const float*)d_in[0];
  const float* tpw  = (const float*)d_in[1];
  const float* tpb  = (const float*)d_in[2];
  const float* pos  = (const float*)d_in[3];
  const float* qkvw = (const float*)d_in[4];
  const float* qkvb = (const float*)d_in[5];
  const float* outw = (const float*)d_in[6];
  const float* outb = (const float*)d_in[7];
  const float* ln1w = (const float*)d_in[8];
  const float* ln1b = (const float*)d_in[9];
  const float* ff1w = (const float*)d_in[10];
  const float* ff1b = (const float*)d_in[11];
  const float* ff2w = (const float*)d_in[12];
  const float* ff2b = (const float*)d_in[13];
  const float* ln2w = (const float*)d_in[14];
  const float* ln2b = (const float*)d_in[15];
  const float* lnfw = (const float*)d_in[16];
  const float* lnfb = (const float*)d_in[17];
  const float* clnw = (const float*)d_in[18];
  const float* clnb = (const float*)d_in[19];
  const float* cw   = (const float*)d_in[20];
  const float* cb   = (const float*)d_in[21];
  unsigned short* wsb = (unsigned short*)d_ws;

  int B = in_sizes[0] / 256;

  hipLaunchKernelGGL(prep_w, dim3((WS_ELEMS + 255) / 256), dim3(256), 0, stream,
                     tpw, qkvw, outw, ff1w, ff2w, wsb);
  hipLaunchKernelGGL(tx_fused, dim3(B / BS), dim3(256), 0, stream,
                     x, wsb, tpb, pos, qkvb, outb, ln1w, ln1b, ff1b, ff2b,
                     ln2w, ln2b, lnfw, lnfb, clnw, clnb, cw, cb, (float*)d_out);
}

// Round 13
// 945.992 us; speedup vs baseline: 1.0947x; 1.0947x over previous
//
#include <hip/hip_runtime.h>

// ============================================================================
// CategoryHead r13: r8 base (bit-exact chain, 720us) + wave-private LDS
// B-prefetch via global_load_lds (zero registers, no barriers — vmcnt is
// per-wave). Pattern per phase: read prefetched B -> issue next PF -> MFMAs.
// Prefetched (each consumed right after a barrier): QKV-nc0, out-proj B,
// ff1-fc0 B, ff2-fc B (all fc), next-layer QKV-nc0.
// Same weight bytes -> absmax must remain exactly 0.00390625.
// LDS 37.4 -> 68.5 KB (still 2 blocks/CU).
// ============================================================================

#define DEV static __device__ __forceinline__

typedef __attribute__((ext_vector_type(8))) short short8;
typedef __attribute__((ext_vector_type(4))) float f32x4;

#define BS    32
#define MROWS 64
#define PITCH 136
#define XP    272
#define LEPS  1e-5f

#define OFF_TPW  0
#define OFF_QKVW 65536
#define OFF_OUTW 262144
#define OFF_FF1W 327680
#define OFF_FF2W 589824
#define WS_ELEMS 851968

DEV unsigned short f2b(float f) {            // f32 -> bf16 (RNE)  [r1 verbatim]
  unsigned u = __float_as_uint(f);
  return (unsigned short)((u + 0x7fffu + ((u >> 16) & 1u)) >> 16);
}
DEV float b2f(unsigned short s) { return __uint_as_float((unsigned)s << 16); }

DEV f32x4 MFMA(short8 a, short8 b, f32x4 c) {
  return __builtin_amdgcn_mfma_f32_16x16x32_bf16(a, b, c, 0, 0, 0);
}

DEV float gelu_f(float x) {                  // [r1 verbatim]
  float u = 0.7978845608028654f * (x + 0.044715f * x * x * x);
  float e = __expf(2.0f * u);
  float t = 1.0f - 2.0f / (e + 1.0f);
  return 0.5f * x * (1.0f + t);
}

DEV short8 ldfrag(const unsigned short* tile, int rowBase, int kk, int lane) {
  return *(const short8*)(tile + (rowBase + (lane & 15)) * PITCH + kk * 32 + (lane >> 4) * 8);
}
DEV short8 ldfragX(const unsigned short* tile, int rowBase, int koff, int lane) {
  return *(const short8*)(tile + (rowBase + (lane & 15)) * XP + koff + (lane >> 4) * 8);
}
// B-fragment direct from global (L2-resident weights), r8 verbatim.
DEV short8 ldBg(const unsigned short* __restrict__ base, int pitch, int colBase,
                int koff, int kk, int lane) {
  return *(const short8*)(base + (size_t)(colBase + (lane & 15)) * pitch +
                          koff + kk * 32 + (lane >> 4) * 8);
}

// ---- wave-private LDS B-prefetch (zero registers, per-wave vmcnt) ----------
// Slot (h,kk) of wave w lives at sPF + w*4096 + (h*4+kk)*512 (shorts).
// global_load_lds: LDS dst = wave-uniform base, HW adds lane*16B; global src
// is per-lane = the exact fragment bytes ldBg would read -> bit-identical.
DEV void pf_issue(unsigned short* sPF, int wave, int lane,
                  const unsigned short* __restrict__ base, int pitch,
                  int ncoff, int koff) {
#pragma unroll
  for (int h = 0; h < 2; ++h)
#pragma unroll
    for (int kk = 0; kk < 4; ++kk) {
      int cb = ncoff + (h * 4 + wave) * 16;
      const unsigned short* src = base + (size_t)(cb + (lane & 15)) * pitch +
                                  koff + kk * 32 + (lane >> 4) * 8;
      __builtin_amdgcn_global_load_lds(
          (const __attribute__((address_space(1))) void*)src,
          (__attribute__((address_space(3))) void*)(sPF + wave * 4096 + (h * 4 + kk) * 512),
          16, 0, 0);
    }
}
DEV short8 pf_read(const unsigned short* sPF, int wave, int h, int kk, int lane) {
  return *(const short8*)(sPF + wave * 4096 + (h * 4 + kk) * 512 + lane * 8);
}
#define PF_WAIT() asm volatile("s_waitcnt vmcnt(0)" ::: "memory")

// [r8 verbatim] residual-added val[2][4] -> LN -> bf16 into sTok
DEV void ln_residual_write(f32x4 (&val)[2][4], const float* __restrict__ w,
                           const float* __restrict__ b, unsigned short* sTok,
                           float* sRedP, float* sRedF, int tid) {
  const int wave = tid >> 6, lane = tid & 63, g = lane >> 4, j = lane & 15;
  float ps[4][4], pq[4][4];
#pragma unroll
  for (int rt = 0; rt < 4; ++rt)
#pragma unroll
    for (int r = 0; r < 4; ++r) {
      float v0 = val[0][rt][r], v1 = val[1][rt][r];
      float s = v0 + v1, q = v0 * v0 + v1 * v1;
#pragma unroll
      for (int m = 1; m < 16; m <<= 1) {
        s += __shfl_xor(s, m, 16);
        q += __shfl_xor(q, m, 16);
      }
      ps[rt][r] = s; pq[rt][r] = q;
    }
  if (j == 0) {
#pragma unroll
    for (int rt = 0; rt < 4; ++rt)
#pragma unroll
      for (int r = 0; r < 4; ++r) {
        int row = rt * 16 + g * 4 + r;
        sRedP[row * 8 + wave * 2]     = ps[rt][r];
        sRedP[row * 8 + wave * 2 + 1] = pq[rt][r];
      }
  }
  __syncthreads();
  if (tid < 64) {
    float s = 0.f, q = 0.f;
#pragma unroll
    for (int wv = 0; wv < 4; ++wv) {
      s += sRedP[tid * 8 + wv * 2];
      q += sRedP[tid * 8 + wv * 2 + 1];
    }
    float mean = s * (1.f / 128.f);
    sRedF[tid * 2]     = mean;
    sRedF[tid * 2 + 1] = rsqrtf(q * (1.f / 128.f) - mean * mean + LEPS);
  }
  __syncthreads();
#pragma unroll
  for (int h = 0; h < 2; ++h) {
    int n = (h * 4 + wave) * 16 + j;
    float wn = w[n], bn = b[n];
#pragma unroll
    for (int rt = 0; rt < 4; ++rt)
#pragma unroll
      for (int r = 0; r < 4; ++r) {
        int row = rt * 16 + g * 4 + r;
        float mean = sRedF[row * 2], rstd = sRedF[row * 2 + 1];
        sTok[row * PITCH + n] = f2b((val[h][rt][r] - mean) * rstd * wn + bn);
      }
  }
  __syncthreads();
}

__global__ __launch_bounds__(256)
void prep_w(const float* __restrict__ tpw, const float* __restrict__ qkvw,
            const float* __restrict__ outw, const float* __restrict__ ff1w,
            const float* __restrict__ ff2w, unsigned short* __restrict__ wsb) {
  int i = blockIdx.x * 256 + threadIdx.x;
  if (i >= WS_ELEMS) return;
  float v;
  if (i < OFF_QKVW)      v = tpw[i - OFF_TPW];
  else if (i < OFF_OUTW) v = qkvw[i - OFF_QKVW];
  else if (i < OFF_FF1W) v = outw[i - OFF_OUTW];
  else if (i < OFF_FF2W) v = ff1w[i - OFF_FF1W];
  else                   v = ff2w[i - OFF_FF2W];
  wsb[i] = f2b(v);
}

__global__ __launch_bounds__(256, 2)
void tx_fused(const float* __restrict__ x, const unsigned short* __restrict__ wsb,
              const float* __restrict__ tpb, const float* __restrict__ pos,
              const float* __restrict__ qkvb, const float* __restrict__ outb,
              const float* __restrict__ ln1w, const float* __restrict__ ln1b,
              const float* __restrict__ ff1b, const float* __restrict__ ff2b,
              const float* __restrict__ ln2w, const float* __restrict__ ln2b,
              const float* __restrict__ lnfw, const float* __restrict__ lnfb,
              const float* __restrict__ clnw, const float* __restrict__ clnb,
              const float* __restrict__ cw, const float* __restrict__ cb,
              float* __restrict__ out) {
  __shared__ __align__(16) unsigned short sTok[MROWS * PITCH];
  __shared__ __align__(16) unsigned short sStage[MROWS * PITCH]; // x / o / h
  __shared__ __align__(16) unsigned short sPF[4 * 4096];         // B prefetch
  __shared__ float sRedP[MROWS * 8];
  __shared__ float sRedF[MROWS * 2];

  const int tid  = threadIdx.x;
  const int wave = tid >> 6;
  const int lane = tid & 63;
  const int g = lane >> 4, j = lane & 15;
  const size_t s0 = (size_t)blockIdx.x * BS;

  const unsigned short* tpwB  = wsb + OFF_TPW;
  const unsigned short* qkvwB = wsb + OFF_QKVW;
  const unsigned short* outwB = wsb + OFF_OUTW;
  const unsigned short* ff1wB = wsb + OFF_FF1W;
  const unsigned short* ff2wB = wsb + OFF_FF2W;

  const f32x4 zero4 = {0.f, 0.f, 0.f, 0.f};

  // ---- stage x (both K-chunks, f2b RNE) [r8 verbatim] ----------------------
  {
#pragma unroll
    for (int it = 0; it < 2; ++it) {
      int idx = it * 256 + tid;
      int r = idx >> 4, s = idx & 15;
      const float4* p = (const float4*)(x + (s0 + r) * 256 + s * 16);
      float4 f0 = p[0], f1 = p[1], f2 = p[2], f3 = p[3];
      short8 lo, hi;
      lo[0] = (short)f2b(f0.x); lo[1] = (short)f2b(f0.y);
      lo[2] = (short)f2b(f0.z); lo[3] = (short)f2b(f0.w);
      lo[4] = (short)f2b(f1.x); lo[5] = (short)f2b(f1.y);
      lo[6] = (short)f2b(f1.z); lo[7] = (short)f2b(f1.w);
      hi[0] = (short)f2b(f2.x); hi[1] = (short)f2b(f2.y);
      hi[2] = (short)f2b(f2.z); hi[3] = (short)f2b(f2.w);
      hi[4] = (short)f2b(f3.x); hi[5] = (short)f2b(f3.y);
      hi[6] = (short)f2b(f3.z); hi[7] = (short)f2b(f3.w);
      *(short8*)(sStage + r * XP + s * 16)     = lo;
      *(short8*)(sStage + r * XP + s * 16 + 8) = hi;
    }
  }
  __syncthreads();

  // ---- token projection [r8 verbatim order]; prefetch L0 QKV nc0 ----------
  pf_issue(sPF, wave, lane, qkvwB, 128, 0, 0);

  f32x4 accTP[2][2][2];
#pragma unroll
  for (int nc = 0; nc < 2; ++nc)
#pragma unroll
    for (int h = 0; h < 2; ++h)
#pragma unroll
      for (int rt = 0; rt < 2; ++rt) accTP[nc][h][rt] = zero4;

#pragma unroll
  for (int kc = 0; kc < 2; ++kc)
#pragma unroll
    for (int nc = 0; nc < 2; ++nc)
#pragma unroll
      for (int h = 0; h < 2; ++h) {
        int cb = nc * 128 + (h * 4 + wave) * 16;
        short8 bf[4];
#pragma unroll
        for (int kk = 0; kk < 4; ++kk)
          bf[kk] = ldBg(tpwB, 256, cb, kc * 128, kk, lane);
#pragma unroll
        for (int rt = 0; rt < 2; ++rt)
#pragma unroll
          for (int kk = 0; kk < 4; ++kk)
            accTP[nc][h][rt] = MFMA(ldfragX(sStage, rt * 16, kc * 128 + kk * 32, lane),
                                    bf[kk], accTP[nc][h][rt]);
      }
  __syncthreads();
#pragma unroll
  for (int nc = 0; nc < 2; ++nc)
#pragma unroll
    for (int h = 0; h < 2; ++h) {
      int d = (h * 4 + wave) * 16 + j;
      float bias = tpb[nc * 128 + d] + pos[nc * 128 + d];
#pragma unroll
      for (int rt = 0; rt < 2; ++rt)
#pragma unroll
        for (int r = 0; r < 4; ++r) {
          int sm = rt * 16 + g * 4 + r;
          sTok[(2 * sm + nc) * PITCH + d] = f2b(accTP[nc][h][rt][r] + bias);
        }
    }
  __syncthreads();

  // ============================== layers ===================================
  for (int li = 0; li < 4; ++li) {
    const unsigned short* qkvL = qkvwB + (size_t)li * 49152;
    const unsigned short* outL = outwB + (size_t)li * 16384;
    const unsigned short* ff1L = ff1wB + (size_t)li * 65536;
    const unsigned short* ff2L = ff2wB + (size_t)li * 65536;

    // ---- QKV: nc0 B prefetched; read -> issue PF(out) -> MFMAs ----
    short8 aT[4][4];
#pragma unroll
    for (int rt = 0; rt < 4; ++rt)
#pragma unroll
      for (int kk = 0; kk < 4; ++kk) aT[rt][kk] = ldfrag(sTok, rt * 16, kk, lane);

    f32x4 acc[6][4];
#pragma unroll
    for (int a = 0; a < 6; ++a)
#pragma unroll
      for (int rt = 0; rt < 4; ++rt) acc[a][rt] = zero4;

    PF_WAIT();
    short8 bq[2][4];
#pragma unroll
    for (int h = 0; h < 2; ++h)
#pragma unroll
      for (int kk = 0; kk < 4; ++kk) bq[h][kk] = pf_read(sPF, wave, h, kk, lane);
    pf_issue(sPF, wave, lane, outL, 128, 0, 0);          // out-proj B
#pragma unroll
    for (int h = 0; h < 2; ++h)
#pragma unroll
      for (int rt = 0; rt < 4; ++rt)
#pragma unroll
        for (int kk = 0; kk < 4; ++kk)
          acc[h][rt] = MFMA(aT[rt][kk], bq[h][kk], acc[h][rt]);
#pragma unroll
    for (int nc = 1; nc < 3; ++nc)
#pragma unroll
      for (int h = 0; h < 2; ++h) {
        int cb = nc * 128 + (h * 4 + wave) * 16;
        short8 bf[4];
#pragma unroll
        for (int kk = 0; kk < 4; ++kk) bf[kk] = ldBg(qkvL, 128, cb, 0, kk, lane);
        int a = nc * 2 + h;
#pragma unroll
        for (int rt = 0; rt < 4; ++rt)
#pragma unroll
          for (int kk = 0; kk < 4; ++kk)
            acc[a][rt] = MFMA(aT[rt][kk], bf[kk], acc[a][rt]);
      }
#pragma unroll
    for (int a = 0; a < 6; ++a) {
      int nc = a >> 1, h = a & 1;
      float bv = qkvb[li * 384 + nc * 128 + (h * 4 + wave) * 16 + j];
#pragma unroll
      for (int rt = 0; rt < 4; ++rt) acc[a][rt] += bv;
    }

    // ---- attention [r8 verbatim] ----
#pragma unroll
    for (int hh = 0; hh < 2; ++hh) {
      int head = hh * 4 + wave;
#pragma unroll
      for (int rt = 0; rt < 4; ++rt)
#pragma unroll
        for (int sp = 0; sp < 2; ++sp) {
          int r0 = sp * 2, r1 = r0 + 1;
          float q0 = acc[hh][rt][r0],     q1 = acc[hh][rt][r1];
          float k0 = acc[2 + hh][rt][r0], k1 = acc[2 + hh][rt][r1];
          float s00 = q0 * k0, s01 = q0 * k1, s10 = q1 * k0, s11 = q1 * k1;
#pragma unroll
          for (int m = 1; m < 16; m <<= 1) {
            s00 += __shfl_xor(s00, m, 16);
            s01 += __shfl_xor(s01, m, 16);
            s10 += __shfl_xor(s10, m, 16);
            s11 += __shfl_xor(s11, m, 16);
          }
          s00 *= 0.25f; s01 *= 0.25f; s10 *= 0.25f; s11 *= 0.25f;
          float m0 = fmaxf(s00, s01), m1 = fmaxf(s10, s11);
          float e00 = __expf(s00 - m0), e01 = __expf(s01 - m0);
          float e10 = __expf(s10 - m1), e11 = __expf(s11 - m1);
          float i0 = 1.f / (e00 + e01), i1 = 1.f / (e10 + e11);
          float v0 = acc[4 + hh][rt][r0], v1 = acc[4 + hh][rt][r1];
          float o0 = (e00 * v0 + e01 * v1) * i0;
          float o1 = (e10 * v0 + e11 * v1) * i1;
          int rowb = rt * 16 + g * 4 + r0;
          int col  = head * 16 + j;
          sStage[rowb * PITCH + col]       = f2b(o0);
          sStage[(rowb + 1) * PITCH + col] = f2b(o1);
        }
    }
    __syncthreads();

    // ---- out-proj: B prefetched; read -> issue PF(ff1 fc0) -> MFMAs ----
    short8 aO[4][4];
#pragma unroll
    for (int rt = 0; rt < 4; ++rt)
#pragma unroll
      for (int kk = 0; kk < 4; ++kk) aO[rt][kk] = ldfrag(sStage, rt * 16, kk, lane);

    PF_WAIT();
    short8 bo[2][4];
#pragma unroll
    for (int h = 0; h < 2; ++h)
#pragma unroll
      for (int kk = 0; kk < 4; ++kk) bo[h][kk] = pf_read(sPF, wave, h, kk, lane);
    pf_issue(sPF, wave, lane, ff1L, 128, 0, 0);          // ff1 fc0 B

    f32x4 accO[2][4];
#pragma unroll
    for (int h = 0; h < 2; ++h)
#pragma unroll
      for (int rt = 0; rt < 4; ++rt) accO[h][rt] = zero4;
#pragma unroll
    for (int h = 0; h < 2; ++h)
#pragma unroll
      for (int rt = 0; rt < 4; ++rt)
#pragma unroll
        for (int kk = 0; kk < 4; ++kk)
          accO[h][rt] = MFMA(aO[rt][kk], bo[h][kk], accO[h][rt]);
#pragma unroll
    for (int h = 0; h < 2; ++h) {
      int n = (h * 4 + wave) * 16 + j;
      float ob = outb[li * 128 + n];
#pragma unroll
      for (int rt = 0; rt < 4; ++rt)
#pragma unroll
        for (int r = 0; r < 4; ++r) {
          int row = rt * 16 + g * 4 + r;
          accO[h][rt][r] += ob + b2f(sTok[row * PITCH + n]);
        }
    }
    ln_residual_write(accO, ln1w + li * 128, ln1b + li * 128, sTok, sRedP, sRedF, tid);

    // ---- FFN ----
    short8 aF[4][4];
#pragma unroll
    for (int rt = 0; rt < 4; ++rt)
#pragma unroll
      for (int kk = 0; kk < 4; ++kk) aF[rt][kk] = ldfrag(sTok, rt * 16, kk, lane);

    f32x4 accF[2][4];
#pragma unroll
    for (int h = 0; h < 2; ++h)
#pragma unroll
      for (int rt = 0; rt < 4; ++rt) accF[h][rt] = zero4;

    for (int fc = 0; fc < 4; ++fc) {
      f32x4 hacc[2][4];
#pragma unroll
      for (int h = 0; h < 2; ++h)
#pragma unroll
        for (int rt = 0; rt < 4; ++rt) hacc[h][rt] = zero4;

      // ff1 B: fc0 prefetched (read -> issue PF(ff2 fc0) -> MFMAs); else direct
      if (fc == 0) {
        PF_WAIT();
        short8 b1[2][4];
#pragma unroll
        for (int h = 0; h < 2; ++h)
#pragma unroll
          for (int kk = 0; kk < 4; ++kk) b1[h][kk] = pf_read(sPF, wave, h, kk, lane);
        pf_issue(sPF, wave, lane, ff2L, 512, 0, 0);      // ff2 fc0 B
#pragma unroll
        for (int h = 0; h < 2; ++h)
#pragma unroll
          for (int rt = 0; rt < 4; ++rt)
#pragma unroll
            for (int kk = 0; kk < 4; ++kk)
              hacc[h][rt] = MFMA(aF[rt][kk], b1[h][kk], hacc[h][rt]);
      } else {
#pragma unroll
        for (int h = 0; h < 2; ++h) {
          int cb = fc * 128 + (h * 4 + wave) * 16;
          short8 bf[4];
#pragma unroll
          for (int kk = 0; kk < 4; ++kk) bf[kk] = ldBg(ff1L, 128, cb, 0, kk, lane);
#pragma unroll
          for (int rt = 0; rt < 4; ++rt)
#pragma unroll
            for (int kk = 0; kk < 4; ++kk)
              hacc[h][rt] = MFMA(aF[rt][kk], bf[kk], hacc[h][rt]);
        }
      }
      __syncthreads();   // prev chunk's aH reads complete before overwrite
#pragma unroll
      for (int h = 0; h < 2; ++h) {
        int nl = (h * 4 + wave) * 16 + j;
        float bb = ff1b[li * 512 + fc * 128 + nl];
#pragma unroll
        for (int rt = 0; rt < 4; ++rt)
#pragma unroll
          for (int r = 0; r < 4; ++r) {
            float hv = gelu_f(hacc[h][rt][r] + bb);
            sStage[(rt * 16 + g * 4 + r) * PITCH + nl] = f2b(hv);
          }
      }
      __syncthreads();   // h chunk visible
      short8 aH[4][4];
#pragma unroll
      for (int rt = 0; rt < 4; ++rt)
#pragma unroll
        for (int kk = 0; kk < 4; ++kk) aH[rt][kk] = ldfrag(sStage, rt * 16, kk, lane);

      // ff2 B prefetched: read -> issue next PF -> MFMAs
      PF_WAIT();
      short8 b2[2][4];
#pragma unroll
      for (int h = 0; h < 2; ++h)
#pragma unroll
        for (int kk = 0; kk < 4; ++kk) b2[h][kk] = pf_read(sPF, wave, h, kk, lane);
      if (fc < 3)      pf_issue(sPF, wave, lane, ff2L, 512, 0, (fc + 1) * 128);
      else if (li < 3) pf_issue(sPF, wave, lane, qkvL + 49152, 128, 0, 0);
#pragma unroll
      for (int h = 0; h < 2; ++h)
#pragma unroll
        for (int rt = 0; rt < 4; ++rt)
#pragma unroll
          for (int kk = 0; kk < 4; ++kk)
            accF[h][rt] = MFMA(aH[rt][kk], b2[h][kk], accF[h][rt]);
    }
    // ff2 bias + residual [r8 verbatim]
#pragma unroll
    for (int h = 0; h < 2; ++h) {
      int n = (h * 4 + wave) * 16 + j;
      float fb = ff2b[li * 128 + n];
#pragma unroll
      for (int rt = 0; rt < 4; ++rt)
#pragma unroll
        for (int r = 0; r < 4; ++r) {
          int row = rt * 16 + g * 4 + r;
          accF[h][rt][r] += fb + b2f(sTok[row * PITCH + n]);
        }
    }
    ln_residual_write(accF, ln2w + li * 128, ln2b + li * 128, sTok, sRedP, sRedF, tid);
  }

  // =================== final LN -> pool -> cls head [r8 verbatim] ===========
  {
    int row = tid >> 2, q4 = tid & 3;
    const unsigned short* rp = sTok + row * PITCH + q4 * 32;
    float vb[32];
    float s = 0.f, sq = 0.f;
#pragma unroll
    for (int t8 = 0; t8 < 4; ++t8) {
      short8 v = *(const short8*)(rp + t8 * 8);
#pragma unroll
      for (int e = 0; e < 8; ++e) {
        float f = b2f((unsigned short)v[e]);
        vb[t8 * 8 + e] = f; s += f; sq += f * f;
      }
    }
    s  += __shfl_xor(s, 1, 4);  s  += __shfl_xor(s, 2, 4);
    sq += __shfl_xor(sq, 1, 4); sq += __shfl_xor(sq, 2, 4);
    float mean = s * (1.f / 128.f);
    float rstd = rsqrtf(sq * (1.f / 128.f) - mean * mean + LEPS);
    unsigned short* wp = sTok + row * PITCH + q4 * 32;
#pragma unroll
    for (int c = 0; c < 32; ++c) {
      int col = q4 * 32 + c;
      wp[c] = f2b((vb[c] - mean) * rstd * lnfw[col] + lnfb[col]);
    }
  }
  __syncthreads();
  {
    int sIdx = tid >> 3, oct = tid & 7;
    float pv[16];
    float s = 0.f, sq = 0.f;
#pragma unroll
    for (int t8 = 0; t8 < 2; ++t8) {
      short8 va  = *(const short8*)(sTok + (2 * sIdx) * PITCH + oct * 16 + t8 * 8);
      short8 vb2 = *(const short8*)(sTok + (2 * sIdx + 1) * PITCH + oct * 16 + t8 * 8);
#pragma unroll
      for (int e = 0; e < 8; ++e) {
        float f = 0.5f * (b2f((unsigned short)va[e]) + b2f((unsigned short)vb2[e]));
        pv[t8 * 8 + e] = f; s += f; sq += f * f;
      }
    }
    s  += __shfl_xor(s, 1, 8);  s  += __shfl_xor(s, 2, 8);  s  += __shfl_xor(s, 4, 8);
    sq += __shfl_xor(sq, 1, 8); sq += __shfl_xor(sq, 2, 8); sq += __shfl_xor(sq, 4, 8);
    float mean = s * (1.f / 128.f);
    float rstd = rsqrtf(sq * (1.f / 128.f) - mean * mean + LEPS);
    float gv[16];
#pragma unroll
    for (int c = 0; c < 16; ++c) {
      int col = oct * 16 + c;
      gv[c] = gelu_f((pv[c] - mean) * rstd * clnw[col] + clnb[col]);
    }
#pragma unroll
    for (int cc = 0; cc < 7; ++cc) {
      float p = 0.f;
#pragma unroll
      for (int c = 0; c < 16; ++c) p += gv[c] * cw[cc * 128 + oct * 16 + c];
      p += __shfl_xor(p, 1, 8); p += __shfl_xor(p, 2, 8); p += __shfl_xor(p, 4, 8);
      if (oct == 0) out[(s0 + sIdx) * 7 + cc] = p + cb[cc];
    }
  }
}

extern "C" void kernel_launch(void* const* d_in, const int* in_sizes, int n_in,
                              void* d_out, int out_size, void* d_ws, size_t ws_size,
                              hipStream_t stream) {
  (void)n_in; (void)out_size; (void)ws_size;
  const float* x    = (const float*)d_in[0];
  const float* tpw  = (const float*)d_in[1];
  const float* tpb  = (const float*)d_in[2];
  const float* pos  = (const float*)d_in[3];
  const float* qkvw = (const float*)d_in[4];
  const float* qkvb = (const float*)d_in[5];
  const float* outw = (const float*)d_in[6];
  const float* outb = (const float*)d_in[7];
  const float* ln1w = (const float*)d_in[8];
  const float* ln1b = (const float*)d_in[9];
  const float* ff1w = (const float*)d_in[10];
  const float* ff1b = (const float*)d_in[11];
  const float* ff2w = (const float*)d_in[12];
  const float* ff2b = (const float*)d_in[13];
  const float* ln2w = (const float*)d_in[14];
  const float* ln2b = (const float*)d_in[15];
  const float* lnfw = (const float*)d_in[16];
  const float* lnfb = (const float*)d_in[17];
  const float* clnw = (const float*)d_in[18];
  const float* clnb = (const float*)d_in[19];
  const float* cw   = (const float*)d_in[20];
  const float* cb   = (const float*)d_in[21];
  unsigned short* wsb = (unsigned short*)d_ws;

  int B = in_sizes[0] / 256;

  hipLaunchKernelGGL(prep_w, dim3((WS_ELEMS + 255) / 256), dim3(256), 0, stream,
                     tpw, qkvw, outw, ff1w, ff2w, wsb);
  hipLaunchKernelGGL(tx_fused, dim3(B / BS), dim3(256), 0, stream,
                     x, wsb, tpb, pos, qkvb, outb, ln1w, ln1b, ff1b, ff2b,
                     ln2w, ln2b, lnfw, lnfb, clnw, clnb, cw, cb, (float*)d_out);
}

// Round 14
// 718.221 us; speedup vs baseline: 1.4418x; 1.3171x over previous
//
#include <hip/hip_runtime.h>

// ============================================================================
// CategoryHead FINAL (r8 revert): r1's exact numeric chain; weight staging
// eliminated — B-fragments read directly from L2 as MFMA operands.
//  - Block = 32 samples / 64 token rows, 4 waves (wave owns col-tiles
//    {w, w+4} of each 128-col group; all waves see all rows).
//  - Barriers only at activation handoffs; no prefetch state across barriers
//    (r9/r11/r13: any such state spills at this register pressure).
//  - Verified: 720 us, absmax exactly 0.00390625 (threshold 7.3e-3).
//  - Experiment ledger (all regressed): reg-prefetch 768, dbuf+LN-trade 752,
//    row-split 871, BS=16 1035, LDS-prefetch 946.
// ============================================================================

#define DEV static __device__ __forceinline__

typedef __attribute__((ext_vector_type(8))) short short8;
typedef __attribute__((ext_vector_type(4))) float f32x4;

#define BS    32
#define MROWS 64
#define PITCH 136
#define XP    272
#define LEPS  1e-5f

#define OFF_TPW  0
#define OFF_QKVW 65536
#define OFF_OUTW 262144
#define OFF_FF1W 327680
#define OFF_FF2W 589824
#define WS_ELEMS 851968

DEV unsigned short f2b(float f) {            // f32 -> bf16 (RNE)
  unsigned u = __float_as_uint(f);
  return (unsigned short)((u + 0x7fffu + ((u >> 16) & 1u)) >> 16);
}
DEV float b2f(unsigned short s) { return __uint_as_float((unsigned)s << 16); }

DEV f32x4 MFMA(short8 a, short8 b, f32x4 c) {
  return __builtin_amdgcn_mfma_f32_16x16x32_bf16(a, b, c, 0, 0, 0);
}

DEV float gelu_f(float x) {
  float u = 0.7978845608028654f * (x + 0.044715f * x * x * x);
  float e = __expf(2.0f * u);
  float t = 1.0f - 2.0f / (e + 1.0f);
  return 0.5f * x * (1.0f + t);
}

DEV short8 ldfrag(const unsigned short* tile, int rowBase, int kk, int lane) {
  return *(const short8*)(tile + (rowBase + (lane & 15)) * PITCH + kk * 32 + (lane >> 4) * 8);
}
DEV short8 ldfragX(const unsigned short* tile, int rowBase, int koff, int lane) {
  return *(const short8*)(tile + (rowBase + (lane & 15)) * XP + koff + (lane >> 4) * 8);
}
// B-fragment direct from global (L2-resident weights).
DEV short8 ldBg(const unsigned short* __restrict__ base, int pitch, int colBase,
                int koff, int kk, int lane) {
  return *(const short8*)(base + (size_t)(colBase + (lane & 15)) * pitch +
                          koff + kk * 32 + (lane >> 4) * 8);
}

// residual-added val[2][4] -> LN -> bf16 into sTok (cross-wave, 3 barriers)
DEV void ln_residual_write(f32x4 (&val)[2][4], const float* __restrict__ w,
                           const float* __restrict__ b, unsigned short* sTok,
                           float* sRedP, float* sRedF, int tid) {
  const int wave = tid >> 6, lane = tid & 63, g = lane >> 4, j = lane & 15;
  float ps[4][4], pq[4][4];
#pragma unroll
  for (int rt = 0; rt < 4; ++rt)
#pragma unroll
    for (int r = 0; r < 4; ++r) {
      float v0 = val[0][rt][r], v1 = val[1][rt][r];
      float s = v0 + v1, q = v0 * v0 + v1 * v1;
#pragma unroll
      for (int m = 1; m < 16; m <<= 1) {
        s += __shfl_xor(s, m, 16);
        q += __shfl_xor(q, m, 16);
      }
      ps[rt][r] = s; pq[rt][r] = q;
    }
  if (j == 0) {
#pragma unroll
    for (int rt = 0; rt < 4; ++rt)
#pragma unroll
      for (int r = 0; r < 4; ++r) {
        int row = rt * 16 + g * 4 + r;
        sRedP[row * 8 + wave * 2]     = ps[rt][r];
        sRedP[row * 8 + wave * 2 + 1] = pq[rt][r];
      }
  }
  __syncthreads();
  if (tid < 64) {
    float s = 0.f, q = 0.f;
#pragma unroll
    for (int wv = 0; wv < 4; ++wv) {
      s += sRedP[tid * 8 + wv * 2];
      q += sRedP[tid * 8 + wv * 2 + 1];
    }
    float mean = s * (1.f / 128.f);
    sRedF[tid * 2]     = mean;
    sRedF[tid * 2 + 1] = rsqrtf(q * (1.f / 128.f) - mean * mean + LEPS);
  }
  __syncthreads();
#pragma unroll
  for (int h = 0; h < 2; ++h) {
    int n = (h * 4 + wave) * 16 + j;
    float wn = w[n], bn = b[n];
#pragma unroll
    for (int rt = 0; rt < 4; ++rt)
#pragma unroll
      for (int r = 0; r < 4; ++r) {
        int row = rt * 16 + g * 4 + r;
        float mean = sRedF[row * 2], rstd = sRedF[row * 2 + 1];
        sTok[row * PITCH + n] = f2b((val[h][rt][r] - mean) * rstd * wn + bn);
      }
  }
  __syncthreads();
}

__global__ __launch_bounds__(256)
void prep_w(const float* __restrict__ tpw, const float* __restrict__ qkvw,
            const float* __restrict__ outw, const float* __restrict__ ff1w,
            const float* __restrict__ ff2w, unsigned short* __restrict__ wsb) {
  int i = blockIdx.x * 256 + threadIdx.x;
  if (i >= WS_ELEMS) return;
  float v;
  if (i < OFF_QKVW)      v = tpw[i - OFF_TPW];
  else if (i < OFF_OUTW) v = qkvw[i - OFF_QKVW];
  else if (i < OFF_FF1W) v = outw[i - OFF_OUTW];
  else if (i < OFF_FF2W) v = ff1w[i - OFF_FF1W];
  else                   v = ff2w[i - OFF_FF2W];
  wsb[i] = f2b(v);
}

__global__ __launch_bounds__(256, 2)
void tx_fused(const float* __restrict__ x, const unsigned short* __restrict__ wsb,
              const float* __restrict__ tpb, const float* __restrict__ pos,
              const float* __restrict__ qkvb, const float* __restrict__ outb,
              const float* __restrict__ ln1w, const float* __restrict__ ln1b,
              const float* __restrict__ ff1b, const float* __restrict__ ff2b,
              const float* __restrict__ ln2w, const float* __restrict__ ln2b,
              const float* __restrict__ lnfw, const float* __restrict__ lnfb,
              const float* __restrict__ clnw, const float* __restrict__ clnb,
              const float* __restrict__ cw, const float* __restrict__ cb,
              float* __restrict__ out) {
  __shared__ __align__(16) unsigned short sTok[MROWS * PITCH];
  __shared__ __align__(16) unsigned short sStage[MROWS * PITCH]; // x / o / h
  __shared__ float sRedP[MROWS * 8];
  __shared__ float sRedF[MROWS * 2];

  const int tid  = threadIdx.x;
  const int wave = tid >> 6;
  const int lane = tid & 63;
  const int g = lane >> 4, j = lane & 15;
  const size_t s0 = (size_t)blockIdx.x * BS;

  const unsigned short* tpwB  = wsb + OFF_TPW;
  const unsigned short* qkvwB = wsb + OFF_QKVW;
  const unsigned short* outwB = wsb + OFF_OUTW;
  const unsigned short* ff1wB = wsb + OFF_FF1W;
  const unsigned short* ff2wB = wsb + OFF_FF2W;

  const f32x4 zero4 = {0.f, 0.f, 0.f, 0.f};

  // ---- stage x (both K-chunks, f2b RNE) ------------------------------------
  {
#pragma unroll
    for (int it = 0; it < 2; ++it) {
      int idx = it * 256 + tid;
      int r = idx >> 4, s = idx & 15;
      const float4* p = (const float4*)(x + (s0 + r) * 256 + s * 16);
      float4 f0 = p[0], f1 = p[1], f2 = p[2], f3 = p[3];
      short8 lo, hi;
      lo[0] = (short)f2b(f0.x); lo[1] = (short)f2b(f0.y);
      lo[2] = (short)f2b(f0.z); lo[3] = (short)f2b(f0.w);
      lo[4] = (short)f2b(f1.x); lo[5] = (short)f2b(f1.y);
      lo[6] = (short)f2b(f1.z); lo[7] = (short)f2b(f1.w);
      hi[0] = (short)f2b(f2.x); hi[1] = (short)f2b(f2.y);
      hi[2] = (short)f2b(f2.z); hi[3] = (short)f2b(f2.w);
      hi[4] = (short)f2b(f3.x); hi[5] = (short)f2b(f3.y);
      hi[6] = (short)f2b(f3.z); hi[7] = (short)f2b(f3.w);
      *(short8*)(sStage + r * XP + s * 16)     = lo;
      *(short8*)(sStage + r * XP + s * 16 + 8) = hi;
    }
  }
  __syncthreads();

  // ---- token projection ----------------------------------------------------
  f32x4 accTP[2][2][2];
#pragma unroll
  for (int nc = 0; nc < 2; ++nc)
#pragma unroll
    for (int h = 0; h < 2; ++h)
#pragma unroll
      for (int rt = 0; rt < 2; ++rt) accTP[nc][h][rt] = zero4;

#pragma unroll
  for (int kc = 0; kc < 2; ++kc)
#pragma unroll
    for (int nc = 0; nc < 2; ++nc)
#pragma unroll
      for (int h = 0; h < 2; ++h) {
        int cb = nc * 128 + (h * 4 + wave) * 16;
        short8 bf[4];
#pragma unroll
        for (int kk = 0; kk < 4; ++kk)
          bf[kk] = ldBg(tpwB, 256, cb, kc * 128, kk, lane);
#pragma unroll
        for (int rt = 0; rt < 2; ++rt)
#pragma unroll
          for (int kk = 0; kk < 4; ++kk)
            accTP[nc][h][rt] = MFMA(ldfragX(sStage, rt * 16, kc * 128 + kk * 32, lane),
                                    bf[kk], accTP[nc][h][rt]);
      }
  __syncthreads();
#pragma unroll
  for (int nc = 0; nc < 2; ++nc)
#pragma unroll
    for (int h = 0; h < 2; ++h) {
      int d = (h * 4 + wave) * 16 + j;
      float bias = tpb[nc * 128 + d] + pos[nc * 128 + d];
#pragma unroll
      for (int rt = 0; rt < 2; ++rt)
#pragma unroll
        for (int r = 0; r < 4; ++r) {
          int sm = rt * 16 + g * 4 + r;
          sTok[(2 * sm + nc) * PITCH + d] = f2b(accTP[nc][h][rt][r] + bias);
        }
    }
  __syncthreads();

  // ============================== layers ===================================
  for (int li = 0; li < 4; ++li) {
    const unsigned short* qkvL = qkvwB + (size_t)li * 49152;
    const unsigned short* outL = outwB + (size_t)li * 16384;
    const unsigned short* ff1L = ff1wB + (size_t)li * 65536;
    const unsigned short* ff2L = ff2wB + (size_t)li * 65536;

    // ---- QKV ----
    short8 aT[4][4];
#pragma unroll
    for (int rt = 0; rt < 4; ++rt)
#pragma unroll
      for (int kk = 0; kk < 4; ++kk) aT[rt][kk] = ldfrag(sTok, rt * 16, kk, lane);

    f32x4 acc[6][4];
#pragma unroll
    for (int a = 0; a < 6; ++a)
#pragma unroll
      for (int rt = 0; rt < 4; ++rt) acc[a][rt] = zero4;

#pragma unroll
    for (int nc = 0; nc < 3; ++nc)
#pragma unroll
      for (int h = 0; h < 2; ++h) {
        int cb = nc * 128 + (h * 4 + wave) * 16;
        short8 bf[4];
#pragma unroll
        for (int kk = 0; kk < 4; ++kk) bf[kk] = ldBg(qkvL, 128, cb, 0, kk, lane);
        int a = nc * 2 + h;
#pragma unroll
        for (int rt = 0; rt < 4; ++rt)
#pragma unroll
          for (int kk = 0; kk < 4; ++kk)
            acc[a][rt] = MFMA(aT[rt][kk], bf[kk], acc[a][rt]);
      }
#pragma unroll
    for (int a = 0; a < 6; ++a) {
      int nc = a >> 1, h = a & 1;
      float bv = qkvb[li * 384 + nc * 128 + (h * 4 + wave) * 16 + j];
#pragma unroll
      for (int rt = 0; rt < 4; ++rt) acc[a][rt] += bv;
    }

    // ---- attention ----
#pragma unroll
    for (int hh = 0; hh < 2; ++hh) {
      int head = hh * 4 + wave;
#pragma unroll
      for (int rt = 0; rt < 4; ++rt)
#pragma unroll
        for (int sp = 0; sp < 2; ++sp) {
          int r0 = sp * 2, r1 = r0 + 1;
          float q0 = acc[hh][rt][r0],     q1 = acc[hh][rt][r1];
          float k0 = acc[2 + hh][rt][r0], k1 = acc[2 + hh][rt][r1];
          float s00 = q0 * k0, s01 = q0 * k1, s10 = q1 * k0, s11 = q1 * k1;
#pragma unroll
          for (int m = 1; m < 16; m <<= 1) {
            s00 += __shfl_xor(s00, m, 16);
            s01 += __shfl_xor(s01, m, 16);
            s10 += __shfl_xor(s10, m, 16);
            s11 += __shfl_xor(s11, m, 16);
          }
          s00 *= 0.25f; s01 *= 0.25f; s10 *= 0.25f; s11 *= 0.25f;
          float m0 = fmaxf(s00, s01), m1 = fmaxf(s10, s11);
          float e00 = __expf(s00 - m0), e01 = __expf(s01 - m0);
          float e10 = __expf(s10 - m1), e11 = __expf(s11 - m1);
          float i0 = 1.f / (e00 + e01), i1 = 1.f / (e10 + e11);
          float v0 = acc[4 + hh][rt][r0], v1 = acc[4 + hh][rt][r1];
          float o0 = (e00 * v0 + e01 * v1) * i0;
          float o1 = (e10 * v0 + e11 * v1) * i1;
          int rowb = rt * 16 + g * 4 + r0;
          int col  = head * 16 + j;
          sStage[rowb * PITCH + col]       = f2b(o0);
          sStage[(rowb + 1) * PITCH + col] = f2b(o1);
        }
    }
    __syncthreads();

    // ---- out-proj ----
    short8 aO[4][4];
#pragma unroll
    for (int rt = 0; rt < 4; ++rt)
#pragma unroll
      for (int kk = 0; kk < 4; ++kk) aO[rt][kk] = ldfrag(sStage, rt * 16, kk, lane);

    f32x4 accO[2][4];
#pragma unroll
    for (int h = 0; h < 2; ++h)
#pragma unroll
      for (int rt = 0; rt < 4; ++rt) accO[h][rt] = zero4;
#pragma unroll
    for (int h = 0; h < 2; ++h) {
      int cb = (h * 4 + wave) * 16;
      short8 bf[4];
#pragma unroll
      for (int kk = 0; kk < 4; ++kk) bf[kk] = ldBg(outL, 128, cb, 0, kk, lane);
#pragma unroll
      for (int rt = 0; rt < 4; ++rt)
#pragma unroll
        for (int kk = 0; kk < 4; ++kk)
          accO[h][rt] = MFMA(aO[rt][kk], bf[kk], accO[h][rt]);
    }
#pragma unroll
    for (int h = 0; h < 2; ++h) {
      int n = (h * 4 + wave) * 16 + j;
      float ob = outb[li * 128 + n];
#pragma unroll
      for (int rt = 0; rt < 4; ++rt)
#pragma unroll
        for (int r = 0; r < 4; ++r) {
          int row = rt * 16 + g * 4 + r;
          accO[h][rt][r] += ob + b2f(sTok[row * PITCH + n]);
        }
    }
    ln_residual_write(accO, ln1w + li * 128, ln1b + li * 128, sTok, sRedP, sRedF, tid);

    // ---- FFN ----
    short8 aF[4][4];
#pragma unroll
    for (int rt = 0; rt < 4; ++rt)
#pragma unroll
      for (int kk = 0; kk < 4; ++kk) aF[rt][kk] = ldfrag(sTok, rt * 16, kk, lane);

    f32x4 accF[2][4];
#pragma unroll
    for (int h = 0; h < 2; ++h)
#pragma unroll
      for (int rt = 0; rt < 4; ++rt) accF[h][rt] = zero4;

    for (int fc = 0; fc < 4; ++fc) {
      f32x4 hacc[2][4];
#pragma unroll
      for (int h = 0; h < 2; ++h)
#pragma unroll
        for (int rt = 0; rt < 4; ++rt) hacc[h][rt] = zero4;
#pragma unroll
      for (int h = 0; h < 2; ++h) {
        int cb = fc * 128 + (h * 4 + wave) * 16;
        short8 bf[4];
#pragma unroll
        for (int kk = 0; kk < 4; ++kk) bf[kk] = ldBg(ff1L, 128, cb, 0, kk, lane);
#pragma unroll
        for (int rt = 0; rt < 4; ++rt)
#pragma unroll
          for (int kk = 0; kk < 4; ++kk)
            hacc[h][rt] = MFMA(aF[rt][kk], bf[kk], hacc[h][rt]);
      }
      __syncthreads();   // prev chunk's aH reads complete before overwrite
#pragma unroll
      for (int h = 0; h < 2; ++h) {
        int nl = (h * 4 + wave) * 16 + j;
        float bb = ff1b[li * 512 + fc * 128 + nl];
#pragma unroll
        for (int rt = 0; rt < 4; ++rt)
#pragma unroll
          for (int r = 0; r < 4; ++r) {
            float hv = gelu_f(hacc[h][rt][r] + bb);
            sStage[(rt * 16 + g * 4 + r) * PITCH + nl] = f2b(hv);
          }
      }
      __syncthreads();   // h chunk visible
      short8 aH[4][4];
#pragma unroll
      for (int rt = 0; rt < 4; ++rt)
#pragma unroll
        for (int kk = 0; kk < 4; ++kk) aH[rt][kk] = ldfrag(sStage, rt * 16, kk, lane);
#pragma unroll
      for (int h = 0; h < 2; ++h) {
        int cb = (h * 4 + wave) * 16;    // ff2 W row = output col
        short8 bf[4];
#pragma unroll
        for (int kk = 0; kk < 4; ++kk)
          bf[kk] = ldBg(ff2L, 512, cb, fc * 128, kk, lane);
#pragma unroll
        for (int rt = 0; rt < 4; ++rt)
#pragma unroll
          for (int kk = 0; kk < 4; ++kk)
            accF[h][rt] = MFMA(aH[rt][kk], bf[kk], accF[h][rt]);
      }
    }
#pragma unroll
    for (int h = 0; h < 2; ++h) {
      int n = (h * 4 + wave) * 16 + j;
      float fb = ff2b[li * 128 + n];
#pragma unroll
      for (int rt = 0; rt < 4; ++rt)
#pragma unroll
        for (int r = 0; r < 4; ++r) {
          int row = rt * 16 + g * 4 + r;
          accF[h][rt][r] += fb + b2f(sTok[row * PITCH + n]);
        }
    }
    ln_residual_write(accF, ln2w + li * 128, ln2b + li * 128, sTok, sRedP, sRedF, tid);
  }

  // =================== final LN -> pool -> cls head =========================
  {
    int row = tid >> 2, q4 = tid & 3;
    const unsigned short* rp = sTok + row * PITCH + q4 * 32;
    float vb[32];
    float s = 0.f, sq = 0.f;
#pragma unroll
    for (int t8 = 0; t8 < 4; ++t8) {
      short8 v = *(const short8*)(rp + t8 * 8);
#pragma unroll
      for (int e = 0; e < 8; ++e) {
        float f = b2f((unsigned short)v[e]);
        vb[t8 * 8 + e] = f; s += f; sq += f * f;
      }
    }
    s  += __shfl_xor(s, 1, 4);  s  += __shfl_xor(s, 2, 4);
    sq += __shfl_xor(sq, 1, 4); sq += __shfl_xor(sq, 2, 4);
    float mean = s * (1.f / 128.f);
    float rstd = rsqrtf(sq * (1.f / 128.f) - mean * mean + LEPS);
    unsigned short* wp = sTok + row * PITCH + q4 * 32;
#pragma unroll
    for (int c = 0; c < 32; ++c) {
      int col = q4 * 32 + c;
      wp[c] = f2b((vb[c] - mean) * rstd * lnfw[col] + lnfb[col]);
    }
  }
  __syncthreads();
  {
    int sIdx = tid >> 3, oct = tid & 7;
    float pv[16];
    float s = 0.f, sq = 0.f;
#pragma unroll
    for (int t8 = 0; t8 < 2; ++t8) {
      short8 va  = *(const short8*)(sTok + (2 * sIdx) * PITCH + oct * 16 + t8 * 8);
      short8 vb2 = *(const short8*)(sTok + (2 * sIdx + 1) * PITCH + oct * 16 + t8 * 8);
#pragma unroll
      for (int e = 0; e < 8; ++e) {
        float f = 0.5f * (b2f((unsigned short)va[e]) + b2f((unsigned short)vb2[e]));
        pv[t8 * 8 + e] = f; s += f; sq += f * f;
      }
    }
    s  += __shfl_xor(s, 1, 8);  s  += __shfl_xor(s, 2, 8);  s  += __shfl_xor(s, 4, 8);
    sq += __shfl_xor(sq, 1, 8); sq += __shfl_xor(sq, 2, 8); sq += __shfl_xor(sq, 4, 8);
    float mean = s * (1.f / 128.f);
    float rstd = rsqrtf(sq * (1.f / 128.f) - mean * mean + LEPS);
    float gv[16];
#pragma unroll
    for (int c = 0; c < 16; ++c) {
      int col = oct * 16 + c;
      gv[c] = gelu_f((pv[c] - mean) * rstd * clnw[col] + clnb[col]);
    }
#pragma unroll
    for (int cc = 0; cc < 7; ++cc) {
      float p = 0.f;
#pragma unroll
      for (int c = 0; c < 16; ++c) p += gv[c] * cw[cc * 128 + oct * 16 + c];
      p += __shfl_xor(p, 1, 8); p += __shfl_xor(p, 2, 8); p += __shfl_xor(p, 4, 8);
      if (oct == 0) out[(s0 + sIdx) * 7 + cc] = p + cb[cc];
    }
  }
}

extern "C" void kernel_launch(void* const* d_in, const int* in_sizes, int n_in,
                              void* d_out, int out_size, void* d_ws, size_t ws_size,
                              hipStream_t stream) {
  (void)n_in; (void)out_size; (void)ws_size;
  const float* x    = (const float*)d_in[0];
  const float* tpw  = (const float*)d_in[1];
  const float* tpb  = (const float*)d_in[2];
  const float* pos  = (const float*)d_in[3];
  const float* qkvw = (const float*)d_in[4];
  const float* qkvb = (const float*)d_in[5];
  const float* outw = (const float*)d_in[6];
  const float* outb = (const float*)d_in[7];
  const float* ln1w = (const float*)d_in[8];
  const float* ln1b = (const float*)d_in[9];
  const float* ff1w = (const float*)d_in[10];
  const float* ff1b = (const float*)d_in[11];
  const float* ff2w = (const float*)d_in[12];
  const float* ff2b = (const float*)d_in[13];
  const float* ln2w = (const float*)d_in[14];
  const float* ln2b = (const float*)d_in[15];
  const float* lnfw = (const float*)d_in[16];
  const float* lnfb = (const float*)d_in[17];
  const float* clnw = (const float*)d_in[18];
  const float* clnb = (const float*)d_in[19];
  const float* cw   = (const float*)d_in[20];
  const float* cb   = (const float*)d_in[21];
  unsigned short* wsb = (unsigned short*)d_ws;

  int B = in_sizes[0] / 256;

  hipLaunchKernelGGL(prep_w, dim3((WS_ELEMS + 255) / 256), dim3(256), 0, stream,
                     tpw, qkvw, outw, ff1w, ff2w, wsb);
  hipLaunchKernelGGL(tx_fused, dim3(B / BS), dim3(256), 0, stream,
                     x, wsb, tpb, pos, qkvb, outb, ln1w, ln1b, ff1b, ff2b,
                     ln2w, ln2b, lnfw, lnfb, clnw, clnb, cw, cb, (float*)d_out);
}